// Round 1
// baseline (543.282 us; speedup 1.0000x reference)
//
#include <hip/hip_runtime.h>

typedef unsigned short ushort_t;
typedef __bf16 bf16x8 __attribute__((ext_vector_type(8)));
typedef float f32x4 __attribute__((ext_vector_type(4)));

// sizes (fixed by the problem)
#define NB 8
#define BB 2
#define TT 2048
#define DD 2048
#define FF 8192
#define MM (BB * TT)          // 4096 rows
#define BTD ((size_t)BB * TT * DD)   // 8388608

__device__ __forceinline__ unsigned short f2bf(float f) {
  unsigned int u = __float_as_uint(f);
  u += 0x7FFFu + ((u >> 16) & 1u);
  return (unsigned short)(u >> 16);
}

__device__ __forceinline__ float gelu_tanh(float x) {
  float u = 0.7978845608028654f * (x + 0.044715f * x * x * x);
  float e = __expf(2.0f * u);
  float th = 1.0f - 2.0f / (e + 1.0f);   // robust tanh(u), e=inf -> 1
  return 0.5f * x * (1.0f + th);
}

#define ASYNC_COPY16(gp, lp)                                                   \
  __builtin_amdgcn_global_load_lds(                                            \
      (__attribute__((address_space(1))) void*)(gp),                           \
      (__attribute__((address_space(3))) void*)(lp), 16, 0, 0)

// ---------------------------------------------------------------------------
// fp32 (R x C) -> bf16 transposed (C x R)
__global__ __launch_bounds__(256) void transpose_conv(
    const float* __restrict__ in, ushort_t* __restrict__ out, int R, int C) {
  __shared__ float tile[32][33];
  const int tx = threadIdx.x & 31, ty = threadIdx.x >> 5;
  const int r0 = blockIdx.y * 32, c0 = blockIdx.x * 32;
#pragma unroll
  for (int i = 0; i < 32; i += 8)
    tile[ty + i][tx] = in[(size_t)(r0 + ty + i) * C + (c0 + tx)];
  __syncthreads();
#pragma unroll
  for (int i = 0; i < 32; i += 8)
    out[(size_t)(c0 + ty + i) * R + (r0 + tx)] = f2bf(tile[tx][ty + i]);
}

// ---------------------------------------------------------------------------
// Fused block-attention: one block per (b,t) row.
// Pass 1: per-n sumsq and dot(V, norm_scale*proj_w) -> logits -> softmax.
// Pass 2: h = sum_n alpha_n * V_n (re-reads hit L2/L3).
__global__ __launch_bounds__(256) void attn_fuse(
    const float* __restrict__ blocks, const float* __restrict__ partial,
    const float* __restrict__ proj_w, const float* __restrict__ norm_scale,
    float* __restrict__ h_out, ushort_t* __restrict__ h_bf) {
  const int t = threadIdx.x;
  const int bt = blockIdx.x;               // = b*T + tt
  const size_t rowoff = (size_t)bt * DD;
  const int d0 = t * 4;                    // + second half at d0+1024

  float w[8];
  {
    float4 ns = *(const float4*)(norm_scale + d0);
    float4 pw = *(const float4*)(proj_w + d0);
    w[0] = ns.x * pw.x; w[1] = ns.y * pw.y; w[2] = ns.z * pw.z; w[3] = ns.w * pw.w;
    ns = *(const float4*)(norm_scale + 1024 + d0);
    pw = *(const float4*)(proj_w + 1024 + d0);
    w[4] = ns.x * pw.x; w[5] = ns.y * pw.y; w[6] = ns.z * pw.z; w[7] = ns.w * pw.w;
  }

  float ss[9], dt[9];
#pragma unroll
  for (int n = 0; n < 9; ++n) {
    const float* rp = (n < 8) ? (blocks + (size_t)n * BTD + rowoff)
                              : (partial + rowoff);
    float4 v0 = *(const float4*)(rp + d0);
    float4 v1 = *(const float4*)(rp + 1024 + d0);
    ss[n] = v0.x * v0.x + v0.y * v0.y + v0.z * v0.z + v0.w * v0.w +
            v1.x * v1.x + v1.y * v1.y + v1.z * v1.z + v1.w * v1.w;
    dt[n] = v0.x * w[0] + v0.y * w[1] + v0.z * w[2] + v0.w * w[3] +
            v1.x * w[4] + v1.y * w[5] + v1.z * w[6] + v1.w * w[7];
  }

  __shared__ float red[2][9][4];
  const int lane = t & 63, wv = t >> 6;
#pragma unroll
  for (int n = 0; n < 9; ++n) {
    float a = ss[n], c = dt[n];
#pragma unroll
    for (int off = 32; off > 0; off >>= 1) {
      a += __shfl_down(a, off, 64);
      c += __shfl_down(c, off, 64);
    }
    if (lane == 0) { red[0][n][wv] = a; red[1][n][wv] = c; }
  }
  __syncthreads();
  __shared__ float logit_s[9];
  if (t < 9) {
    float a = red[0][t][0] + red[0][t][1] + red[0][t][2] + red[0][t][3];
    float c = red[1][t][0] + red[1][t][1] + red[1][t][2] + red[1][t][3];
    logit_s[t] = c * rsqrtf(a * (1.0f / (float)DD) + 1e-8f);
  }
  __syncthreads();

  float lg[9], mx = -1e30f;
#pragma unroll
  for (int n = 0; n < 9; ++n) { lg[n] = logit_s[n]; mx = fmaxf(mx, lg[n]); }
  float den = 0.0f;
#pragma unroll
  for (int n = 0; n < 9; ++n) { lg[n] = __expf(lg[n] - mx); den += lg[n]; }
  const float inv = 1.0f / den;

  float h[8] = {0, 0, 0, 0, 0, 0, 0, 0};
#pragma unroll
  for (int n = 0; n < 9; ++n) {
    const float* rp = (n < 8) ? (blocks + (size_t)n * BTD + rowoff)
                              : (partial + rowoff);
    float4 v0 = *(const float4*)(rp + d0);
    float4 v1 = *(const float4*)(rp + 1024 + d0);
    const float a = lg[n] * inv;
    h[0] += a * v0.x; h[1] += a * v0.y; h[2] += a * v0.z; h[3] += a * v0.w;
    h[4] += a * v1.x; h[5] += a * v1.y; h[6] += a * v1.z; h[7] += a * v1.w;
  }

  float4 o0 = {h[0], h[1], h[2], h[3]}, o1 = {h[4], h[5], h[6], h[7]};
  *(float4*)(h_out + rowoff + d0) = o0;
  *(float4*)(h_out + rowoff + 1024 + d0) = o1;
  uint2 p0, p1;
  p0.x = (unsigned)f2bf(h[0]) | ((unsigned)f2bf(h[1]) << 16);
  p0.y = (unsigned)f2bf(h[2]) | ((unsigned)f2bf(h[3]) << 16);
  p1.x = (unsigned)f2bf(h[4]) | ((unsigned)f2bf(h[5]) << 16);
  p1.y = (unsigned)f2bf(h[6]) | ((unsigned)f2bf(h[7]) << 16);
  *(uint2*)(h_bf + rowoff + d0) = p0;
  *(uint2*)(h_bf + rowoff + 1024 + d0) = p1;
}

// ---------------------------------------------------------------------------
// bf16 GEMM, m97 structure: 128x128 tile, BK=32, 4 waves (2x2), each wave
// computes 64x64 via 4x4 16x16x32 MFMA fragments. B given as B^T (N x K).
// EPI=0: C = gelu(A@B) -> bf16.  EPI=1: C = A@B + addend -> fp32.
template <int EPI>
__global__ __launch_bounds__(256) void gemm_bt(
    const ushort_t* __restrict__ A, const ushort_t* __restrict__ BT,
    const int K, const int N, ushort_t* __restrict__ Cb,
    const float* __restrict__ addend, float* __restrict__ Cf) {
  __shared__ __align__(16) ushort_t As[128 * 32];
  __shared__ __align__(16) ushort_t Bs[128 * 32];
  const int t = threadIdx.x;
  const int lane = t & 63, wv = t >> 6;
  const int row0 = blockIdx.y * 128, col0 = blockIdx.x * 128;
  const int wr = (wv >> 1) * 64, wc = (wv & 1) * 64;
  const int fr = lane & 15, fk = (lane >> 4) * 8;

  // staging: thread t loads 16B at tile row t/4, col (t%4)*8 (+64-row chunk)
  const int srow = t >> 2;
  const int scol = (t & 3) * 8;
  const ushort_t* gA = A + (size_t)(row0 + srow) * K + scol;
  const ushort_t* gB = BT + (size_t)(col0 + srow) * K + scol;
  const size_t rstep = (size_t)64 * K;
  // wave-uniform LDS bases (hw writes base + lane*16)
  ushort_t* lA0 = As + wv * 512;
  ushort_t* lA1 = As + 2048 + wv * 512;
  ushort_t* lB0 = Bs + wv * 512;
  ushort_t* lB1 = Bs + 2048 + wv * 512;

  f32x4 acc[4][4];
#pragma unroll
  for (int m = 0; m < 4; ++m)
#pragma unroll
    for (int n = 0; n < 4; ++n) {
      f32x4 z = {0.f, 0.f, 0.f, 0.f};
      acc[m][n] = z;
    }

  for (int k0 = 0; k0 < K; k0 += 32) {
    ASYNC_COPY16(gA + k0, lA0);
    ASYNC_COPY16(gA + rstep + k0, lA1);
    ASYNC_COPY16(gB + k0, lB0);
    ASYNC_COPY16(gB + rstep + k0, lB1);
    __syncthreads();

    bf16x8 af[4], bfr[4];
#pragma unroll
    for (int m = 0; m < 4; ++m)
      af[m] = *(const bf16x8*)(As + (wr + m * 16 + fr) * 32 + fk);
#pragma unroll
    for (int n = 0; n < 4; ++n)
      bfr[n] = *(const bf16x8*)(Bs + (wc + n * 16 + fr) * 32 + fk);
#pragma unroll
    for (int m = 0; m < 4; ++m)
#pragma unroll
      for (int n = 0; n < 4; ++n)
        acc[m][n] = __builtin_amdgcn_mfma_f32_16x16x32_bf16(af[m], bfr[n],
                                                            acc[m][n], 0, 0, 0);
    __syncthreads();
  }

  const int r4 = (lane >> 4) * 4;
#pragma unroll
  for (int m = 0; m < 4; ++m)
#pragma unroll
    for (int n = 0; n < 4; ++n)
#pragma unroll
      for (int r = 0; r < 4; ++r) {
        const int row = row0 + wr + m * 16 + r4 + r;
        const int col = col0 + wc + n * 16 + fr;
        const float v = acc[m][n][r];
        if (EPI == 0) {
          Cb[(size_t)row * N + col] = f2bf(gelu_tanh(v));
        } else {
          const size_t idx = (size_t)row * N + col;
          Cf[idx] = v + addend[idx];
        }
      }
}

// ---------------------------------------------------------------------------
extern "C" void kernel_launch(void* const* d_in, const int* in_sizes, int n_in,
                              void* d_out, int out_size, void* d_ws,
                              size_t ws_size, hipStream_t stream) {
  const float* blocks = (const float*)d_in[0];
  const float* partial = (const float*)d_in[1];
  const float* proj_w = (const float*)d_in[2];
  const float* norm_scale = (const float*)d_in[3];
  const float* w1 = (const float*)d_in[4];
  const float* w2 = (const float*)d_in[5];

  float* out = (float*)d_out;
  float* h_out = out;                 // [B,T,D] fp32
  float* new_partial = out + BTD;     // [B,T,D] fp32

  char* ws = (char*)d_ws;
  ushort_t* h_bf = (ushort_t*)ws;                              // 16 MB
  ushort_t* w1T = (ushort_t*)(ws + (size_t)16777216);          // 32 MB (F x D)
  ushort_t* w2T = (ushort_t*)(ws + (size_t)16777216 + 33554432);       // 32 MB (D x F)
  ushort_t* act = (ushort_t*)(ws + (size_t)16777216 + 2 * 33554432ull);  // 64 MB (M x F)

  // weight convert + transpose to (N x K) bf16
  transpose_conv<<<dim3(FF / 32, DD / 32), 256, 0, stream>>>(w1, w1T, DD, FF);
  transpose_conv<<<dim3(DD / 32, FF / 32), 256, 0, stream>>>(w2, w2T, FF, DD);

  // fused attention -> h (fp32 out) + h (bf16 for GEMM)
  attn_fuse<<<MM, 256, 0, stream>>>(blocks, partial, proj_w, norm_scale, h_out,
                                    h_bf);

  // FFN: act = gelu(h @ W1) ; new_partial = act @ W2 + partial
  gemm_bt<0><<<dim3(FF / 128, MM / 128), 256, 0, stream>>>(
      h_bf, w1T, DD, FF, act, nullptr, nullptr);
  gemm_bt<1><<<dim3(DD / 128, MM / 128), 256, 0, stream>>>(
      act, w2T, FF, DD, nullptr, partial, new_partial);
}

// Round 2
// 423.366 us; speedup vs baseline: 1.2832x; 1.2832x over previous
//
#include <hip/hip_runtime.h>

typedef unsigned short ushort_t;
typedef __bf16 bf16x8 __attribute__((ext_vector_type(8)));
typedef float f32x4 __attribute__((ext_vector_type(4)));

// sizes (fixed by the problem)
#define NB 8
#define BB 2
#define TT 2048
#define DD 2048
#define FF 8192
#define MM (BB * TT)          // 4096 rows
#define BTD ((size_t)BB * TT * DD)   // 8388608

__device__ __forceinline__ unsigned short f2bf(float f) {
  unsigned int u = __float_as_uint(f);
  u += 0x7FFFu + ((u >> 16) & 1u);
  return (unsigned short)(u >> 16);
}

__device__ __forceinline__ float gelu_tanh(float x) {
  float u = 0.7978845608028654f * (x + 0.044715f * x * x * x);
  float e = __expf(2.0f * u);
  float th = 1.0f - 2.0f / (e + 1.0f);   // robust tanh(u), e=inf -> 1
  return 0.5f * x * (1.0f + th);
}

#define ASYNC_COPY16(gp, lp)                                                   \
  __builtin_amdgcn_global_load_lds(                                            \
      (__attribute__((address_space(1))) void*)(gp),                           \
      (__attribute__((address_space(3))) void*)(lp), 16, 0, 0)

// ---------------------------------------------------------------------------
// fp32 (R x C) -> bf16 transposed (C x R)
__global__ __launch_bounds__(256) void transpose_conv(
    const float* __restrict__ in, ushort_t* __restrict__ out, int R, int C) {
  __shared__ float tile[32][33];
  const int tx = threadIdx.x & 31, ty = threadIdx.x >> 5;
  const int r0 = blockIdx.y * 32, c0 = blockIdx.x * 32;
#pragma unroll
  for (int i = 0; i < 32; i += 8)
    tile[ty + i][tx] = in[(size_t)(r0 + ty + i) * C + (c0 + tx)];
  __syncthreads();
#pragma unroll
  for (int i = 0; i < 32; i += 8)
    out[(size_t)(c0 + ty + i) * R + (r0 + tx)] = f2bf(tile[tx][ty + i]);
}

// ---------------------------------------------------------------------------
// Fused block-attention: one block per (b,t) row.
__global__ __launch_bounds__(256) void attn_fuse(
    const float* __restrict__ blocks, const float* __restrict__ partial,
    const float* __restrict__ proj_w, const float* __restrict__ norm_scale,
    float* __restrict__ h_out, ushort_t* __restrict__ h_bf) {
  const int t = threadIdx.x;
  const int bt = blockIdx.x;
  const size_t rowoff = (size_t)bt * DD;
  const int d0 = t * 4;

  float w[8];
  {
    float4 ns = *(const float4*)(norm_scale + d0);
    float4 pw = *(const float4*)(proj_w + d0);
    w[0] = ns.x * pw.x; w[1] = ns.y * pw.y; w[2] = ns.z * pw.z; w[3] = ns.w * pw.w;
    ns = *(const float4*)(norm_scale + 1024 + d0);
    pw = *(const float4*)(proj_w + 1024 + d0);
    w[4] = ns.x * pw.x; w[5] = ns.y * pw.y; w[6] = ns.z * pw.z; w[7] = ns.w * pw.w;
  }

  float ss[9], dt[9];
#pragma unroll
  for (int n = 0; n < 9; ++n) {
    const float* rp = (n < 8) ? (blocks + (size_t)n * BTD + rowoff)
                              : (partial + rowoff);
    float4 v0 = *(const float4*)(rp + d0);
    float4 v1 = *(const float4*)(rp + 1024 + d0);
    ss[n] = v0.x * v0.x + v0.y * v0.y + v0.z * v0.z + v0.w * v0.w +
            v1.x * v1.x + v1.y * v1.y + v1.z * v1.z + v1.w * v1.w;
    dt[n] = v0.x * w[0] + v0.y * w[1] + v0.z * w[2] + v0.w * w[3] +
            v1.x * w[4] + v1.y * w[5] + v1.z * w[6] + v1.w * w[7];
  }

  __shared__ float red[2][9][4];
  const int lane = t & 63, wv = t >> 6;
#pragma unroll
  for (int n = 0; n < 9; ++n) {
    float a = ss[n], c = dt[n];
#pragma unroll
    for (int off = 32; off > 0; off >>= 1) {
      a += __shfl_down(a, off, 64);
      c += __shfl_down(c, off, 64);
    }
    if (lane == 0) { red[0][n][wv] = a; red[1][n][wv] = c; }
  }
  __syncthreads();
  __shared__ float logit_s[9];
  if (t < 9) {
    float a = red[0][t][0] + red[0][t][1] + red[0][t][2] + red[0][t][3];
    float c = red[1][t][0] + red[1][t][1] + red[1][t][2] + red[1][t][3];
    logit_s[t] = c * rsqrtf(a * (1.0f / (float)DD) + 1e-8f);
  }
  __syncthreads();

  float lg[9], mx = -1e30f;
#pragma unroll
  for (int n = 0; n < 9; ++n) { lg[n] = logit_s[n]; mx = fmaxf(mx, lg[n]); }
  float den = 0.0f;
#pragma unroll
  for (int n = 0; n < 9; ++n) { lg[n] = __expf(lg[n] - mx); den += lg[n]; }
  const float inv = 1.0f / den;

  float h[8] = {0, 0, 0, 0, 0, 0, 0, 0};
#pragma unroll
  for (int n = 0; n < 9; ++n) {
    const float* rp = (n < 8) ? (blocks + (size_t)n * BTD + rowoff)
                              : (partial + rowoff);
    float4 v0 = *(const float4*)(rp + d0);
    float4 v1 = *(const float4*)(rp + 1024 + d0);
    const float a = lg[n] * inv;
    h[0] += a * v0.x; h[1] += a * v0.y; h[2] += a * v0.z; h[3] += a * v0.w;
    h[4] += a * v1.x; h[5] += a * v1.y; h[6] += a * v1.z; h[7] += a * v1.w;
  }

  float4 o0 = {h[0], h[1], h[2], h[3]}, o1 = {h[4], h[5], h[6], h[7]};
  *(float4*)(h_out + rowoff + d0) = o0;
  *(float4*)(h_out + rowoff + 1024 + d0) = o1;
  uint2 p0, p1;
  p0.x = (unsigned)f2bf(h[0]) | ((unsigned)f2bf(h[1]) << 16);
  p0.y = (unsigned)f2bf(h[2]) | ((unsigned)f2bf(h[3]) << 16);
  p1.x = (unsigned)f2bf(h[4]) | ((unsigned)f2bf(h[5]) << 16);
  p1.y = (unsigned)f2bf(h[6]) | ((unsigned)f2bf(h[7]) << 16);
  *(uint2*)(h_bf + rowoff + d0) = p0;
  *(uint2*)(h_bf + rowoff + 1024 + d0) = p1;
}

// ---------------------------------------------------------------------------
// 256-row 8-phase bf16 GEMM (HK-derived template, plain HIP).
// BM=256, BK=64, 8 waves (2M x 4N), per-wave output 128 x (BN/4).
// LDS: A[256][64] + B[BN][64] bf16, row byte-stride 128, col-swizzled
// byte ^= ((row&7)<<4); double-buffered as two STATIC arrays so the compiler
// proves no aliasing between staged writes (buf^1) and ds_reads (buf).
// Per K-tile: 4 phases {ds_read (4 or NF+4) ; barrier ; setprio ; MFMA ;
// setprio ; barrier}, all stage loads for t+1 issued in phase A of tile t.
// EPI=0: C = gelu(A@B) -> bf16.  EPI=1: C = A@B + addend -> fp32.
template <int BN, int EPI>
__global__ __launch_bounds__(512) void gemm256(
    const ushort_t* __restrict__ A, const ushort_t* __restrict__ BT,
    const int K, const int N, const int GX, ushort_t* __restrict__ Cb,
    const float* __restrict__ addend, float* __restrict__ Cf) {
  constexpr int BM = 256;
  constexpr int WCN = BN / 4;     // wave col span
  constexpr int MF = 8;           // m-frags per wave (128 rows)
  constexpr int NF = WCN / 16;    // n-frags per wave
  constexpr int MH = 4;           // m-frags per phase
  constexpr int CH_B = BN / 128;  // 8KB chunks per B half
  constexpr int ABYTES = BM * 64 * 2;  // 32768

  __shared__ __align__(16) ushort_t lds0[(BM + BN) * 64];
  __shared__ __align__(16) ushort_t lds1[(BM + BN) * 64];

  const int t = threadIdx.x;
  const int lane = t & 63, wv = t >> 6;
  const int wr = wv >> 2, wc = wv & 3;
  const int fr = lane & 15;

  // T1: XCD-aware swizzle (grid % 8 == 0 in both instantiations)
  const int nwg = gridDim.x;
  const int wg = blockIdx.x;
  const int swz = (wg & 7) * (nwg >> 3) + (wg >> 3);
  const int bx = swz % GX, by = swz / GX;
  const int row0 = by * BM, col0 = bx * BN;

  // staging: thread t covers 16B at (row = chunk*64 + t/8, colbyte pre-swz)
  const int sr = t >> 3;
  const int scolb = ((t & 7) * 16) ^ ((sr & 7) << 4);  // inverse-swizzled src
  const ushort_t* gA = A + (size_t)(row0 + sr) * K + (scolb >> 1);
  const ushort_t* gB = BT + (size_t)(col0 + sr) * K + (scolb >> 1);

#define STAGE(DST, KT)                                                         \
  {                                                                            \
    const int _k0 = (KT)*64;                                                   \
    for (int j = 0; j < 4; ++j)                                                \
      ASYNC_COPY16(gA + (size_t)(j * 64) * K + _k0,                            \
                   &DST[j * 4096 + wv * 512]);                                 \
    for (int j = 0; j < 2 * CH_B; ++j)                                         \
      ASYNC_COPY16(gB + (size_t)(j * 64) * K + _k0,                            \
                   &DST[BM * 64 + j * 4096 + wv * 512]);                       \
  }

  // frag read offsets: row*128 + ((ks*64 + (lane>>4)*16) ^ ((row&7)<<4));
  // row&7 == fr&7 for every frag row, so the XOR term is lane-constant.
  const int s_lane = (fr & 7) << 4;
  const int offk0 = ((lane >> 4) * 16) ^ s_lane;
  const int offk1 = (64 + (lane >> 4) * 16) ^ s_lane;
  const int aoffA = (wr * 128 + fr) * 128;  // + m*2048
  int boffB[NF];
#pragma unroll
  for (int n = 0; n < NF; ++n)
    boffB[n] = ABYTES + (wc * WCN + n * 16 + fr) * 128;

  f32x4 acc[MF][NF];
#pragma unroll
  for (int m = 0; m < MF; ++m)
#pragma unroll
    for (int n = 0; n < NF; ++n) {
      f32x4 z = {0.f, 0.f, 0.f, 0.f};
      acc[m][n] = z;
    }

#define TILE(SRC, DST, STAGEKT, DOSTAGE)                                       \
  {                                                                            \
    const char* _L = (const char*)SRC;                                         \
    bf16x8 bfr[NF], afr[MH];                                                   \
    /* phase A: ks0, m 0..3 */                                                 \
    for (int n = 0; n < NF; ++n)                                               \
      bfr[n] = *(const bf16x8*)(_L + boffB[n] + offk0);                        \
    for (int m = 0; m < MH; ++m)                                               \
      afr[m] = *(const bf16x8*)(_L + aoffA + m * 2048 + offk0);                \
    if (DOSTAGE) STAGE(DST, STAGEKT);                                          \
    __builtin_amdgcn_s_barrier();                                              \
    __builtin_amdgcn_s_setprio(1);                                             \
    for (int m = 0; m < MH; ++m)                                               \
      for (int n = 0; n < NF; ++n)                                             \
        acc[m][n] = __builtin_amdgcn_mfma_f32_16x16x32_bf16(afr[m], bfr[n],    \
                                                            acc[m][n], 0, 0, 0); \
    __builtin_amdgcn_s_setprio(0);                                             \
    __builtin_amdgcn_s_barrier();                                              \
    /* phase B: ks0, m 4..7 */                                                 \
    for (int m = 0; m < MH; ++m)                                               \
      afr[m] = *(const bf16x8*)(_L + aoffA + (MH + m) * 2048 + offk0);         \
    __builtin_amdgcn_s_barrier();                                              \
    __builtin_amdgcn_s_setprio(1);                                             \
    for (int m = 0; m < MH; ++m)                                               \
      for (int n = 0; n < NF; ++n)                                             \
        acc[MH + m][n] = __builtin_amdgcn_mfma_f32_16x16x32_bf16(              \
            afr[m], bfr[n], acc[MH + m][n], 0, 0, 0);                          \
    __builtin_amdgcn_s_setprio(0);                                             \
    __builtin_amdgcn_s_barrier();                                              \
    /* phase C: ks1, m 0..3 */                                                 \
    for (int n = 0; n < NF; ++n)                                               \
      bfr[n] = *(const bf16x8*)(_L + boffB[n] + offk1);                        \
    for (int m = 0; m < MH; ++m)                                               \
      afr[m] = *(const bf16x8*)(_L + aoffA + m * 2048 + offk1);                \
    __builtin_amdgcn_s_barrier();                                              \
    __builtin_amdgcn_s_setprio(1);                                             \
    for (int m = 0; m < MH; ++m)                                               \
      for (int n = 0; n < NF; ++n)                                             \
        acc[m][n] = __builtin_amdgcn_mfma_f32_16x16x32_bf16(afr[m], bfr[n],    \
                                                            acc[m][n], 0, 0, 0); \
    __builtin_amdgcn_s_setprio(0);                                             \
    __builtin_amdgcn_s_barrier();                                              \
    /* phase D: ks1, m 4..7 */                                                 \
    for (int m = 0; m < MH; ++m)                                               \
      afr[m] = *(const bf16x8*)(_L + aoffA + (MH + m) * 2048 + offk1);         \
    __builtin_amdgcn_s_barrier();                                              \
    __builtin_amdgcn_s_setprio(1);                                             \
    for (int m = 0; m < MH; ++m)                                               \
      for (int n = 0; n < NF; ++n)                                             \
        acc[MH + m][n] = __builtin_amdgcn_mfma_f32_16x16x32_bf16(              \
            afr[m], bfr[n], acc[MH + m][n], 0, 0, 0);                          \
    __builtin_amdgcn_s_setprio(0);                                             \
    __syncthreads(); /* tile boundary: drains vmcnt+lgkm, syncs waves */       \
  }

  STAGE(lds0, 0);
  __syncthreads();

  const int NT = K >> 6;  // K-tiles (K % 64 == 0, NT even)
  for (int kt = 0; kt < NT; kt += 2) {
    TILE(lds0, lds1, kt + 1, (kt + 1 < NT));
    TILE(lds1, lds0, kt + 2, (kt + 2 < NT));
  }

  const int r4 = (lane >> 4) * 4;
#pragma unroll
  for (int m = 0; m < MF; ++m) {
    const int grow = row0 + wr * 128 + m * 16 + r4;
#pragma unroll
    for (int n = 0; n < NF; ++n) {
      const int gcol = col0 + wc * WCN + n * 16 + fr;
#pragma unroll
      for (int r = 0; r < 4; ++r) {
        const float v = acc[m][n][r];
        const size_t idx = (size_t)(grow + r) * N + gcol;
        if (EPI == 0) {
          Cb[idx] = f2bf(gelu_tanh(v));
        } else {
          Cf[idx] = v + addend[idx];
        }
      }
    }
  }
#undef TILE
#undef STAGE
}

// ---------------------------------------------------------------------------
extern "C" void kernel_launch(void* const* d_in, const int* in_sizes, int n_in,
                              void* d_out, int out_size, void* d_ws,
                              size_t ws_size, hipStream_t stream) {
  const float* blocks = (const float*)d_in[0];
  const float* partial = (const float*)d_in[1];
  const float* proj_w = (const float*)d_in[2];
  const float* norm_scale = (const float*)d_in[3];
  const float* w1 = (const float*)d_in[4];
  const float* w2 = (const float*)d_in[5];

  float* out = (float*)d_out;
  float* h_out = out;                 // [B,T,D] fp32
  float* new_partial = out + BTD;     // [B,T,D] fp32

  char* ws = (char*)d_ws;
  ushort_t* h_bf = (ushort_t*)ws;                                        // 16 MB
  ushort_t* w1T = (ushort_t*)(ws + (size_t)16777216);                    // 32 MB (F x D)
  ushort_t* w2T = (ushort_t*)(ws + (size_t)16777216 + 33554432);         // 32 MB (D x F)
  ushort_t* act = (ushort_t*)(ws + (size_t)16777216 + 2 * 33554432ull);  // 64 MB (M x F)

  // weight convert + transpose to (N x K) bf16
  transpose_conv<<<dim3(FF / 32, DD / 32), 256, 0, stream>>>(w1, w1T, DD, FF);
  transpose_conv<<<dim3(DD / 32, FF / 32), 256, 0, stream>>>(w2, w2T, FF, DD);

  // fused attention -> h (fp32 out) + h (bf16 for GEMM)
  attn_fuse<<<MM, 256, 0, stream>>>(blocks, partial, proj_w, norm_scale, h_out,
                                    h_bf);

  // FFN: act = gelu(h @ W1) ; new_partial = act @ W2 + partial
  gemm256<256, 0><<<(FF / 256) * (MM / 256), 512, 0, stream>>>(
      h_bf, w1T, DD, FF, FF / 256, act, nullptr, nullptr);
  gemm256<128, 1><<<(DD / 128) * (MM / 256), 512, 0, stream>>>(
      act, w2T, FF, DD, DD / 128, nullptr, partial, new_partial);
}